// Round 8
// baseline (134.478 us; speedup 1.0000x reference)
//
#include <hip/hip_runtime.h>

typedef unsigned short u16;
typedef __attribute__((ext_vector_type(4))) float f32x4;
typedef __attribute__((ext_vector_type(16))) float f32x16;
typedef __attribute__((ext_vector_type(8))) short bf16x8;
typedef __attribute__((ext_vector_type(4))) unsigned short u16x4;
typedef __attribute__((ext_vector_type(4))) unsigned u32x4;
typedef __attribute__((ext_vector_type(2))) unsigned uv2;

__device__ __forceinline__ u16 f2bf(float f) {
  unsigned u = __float_as_uint(f);
  u += 0x7FFFu + ((u >> 16) & 1u);
  return (u16)(u >> 16);
}
__device__ __forceinline__ float bf2f(u16 v) {
  return __uint_as_float(((unsigned)v) << 16);
}

__device__ __forceinline__ void gload_lds16(const u16* g, u16* l) {
  __builtin_amdgcn_global_load_lds((const __attribute__((address_space(1))) void*)g,
                                   (__attribute__((address_space(3))) void*)l, 16, 0, 0);
}

__device__ __forceinline__ unsigned cvt_pk_bf16(float lo, float hi) {
  unsigned r;
  asm("v_cvt_pk_bf16_f32 %0, %1, %2" : "=v"(r) : "v"(lo), "v"(hi));
  return r;
}

__device__ __forceinline__ float fexp2(float x) {
#if __has_builtin(__builtin_amdgcn_exp2f)
  return __builtin_amdgcn_exp2f(x);
#else
  return __expf(x * 0.6931471805599453f);
#endif
}

// ---------------- convert fp32 -> bf16 ----------------
__global__ __launch_bounds__(256) void convert_f32_bf16(const float* __restrict__ in,
                                                        u16* __restrict__ out, int n) {
  int i = (blockIdx.x * 256 + threadIdx.x) * 4;
  if (i >= n) return;
  float4 v = *(const float4*)&in[i];
  out[i + 0] = f2bf(v.x);
  out[i + 1] = f2bf(v.y);
  out[i + 2] = f2bf(v.z);
  out[i + 3] = f2bf(v.w);
}

// ---------------- transpose fp32 (R x C) -> bf16 (C x R) ----------------
__global__ __launch_bounds__(256) void transpose_f32_bf16(const float* __restrict__ in,
                                                          u16* __restrict__ out,
                                                          int R, int C) {
  __shared__ float tile[32][33];
  int c0 = blockIdx.x * 32, r0 = blockIdx.y * 32;
  int tx = threadIdx.x, ty = threadIdx.y;
  for (int j = 0; j < 32; j += 8)
    tile[ty + j][tx] = in[(size_t)(r0 + ty + j) * C + c0 + tx];
  __syncthreads();
  for (int j = 0; j < 32; j += 8)
    out[(size_t)(c0 + ty + j) * R + r0 + tx] = f2bf(tile[tx][ty + j]);
}

// ---------------- fused wq/wk/wv transpose -> wqkvT [2560][2048] ----------------
__global__ __launch_bounds__(256) void transpose_wqkv(const float* __restrict__ wq,
                                                      const float* __restrict__ wk,
                                                      const float* __restrict__ wv,
                                                      u16* __restrict__ out) {
  __shared__ float tile[32][33];
  int bx = blockIdx.x, r0 = blockIdx.y * 32;
  const float* src;
  int C, cc0;
  if (bx < 64) { src = wq; C = 2048; cc0 = bx * 32; }
  else if (bx < 72) { src = wk; C = 256; cc0 = (bx - 64) * 32; }
  else { src = wv; C = 256; cc0 = (bx - 72) * 32; }
  int tx = threadIdx.x, ty = threadIdx.y;
  for (int j = 0; j < 32; j += 8)
    tile[ty + j][tx] = src[(size_t)(r0 + ty + j) * C + cc0 + tx];
  __syncthreads();
  for (int j = 0; j < 32; j += 8)
    out[(size_t)(bx * 32 + ty + j) * 2048 + r0 + tx] = f2bf(tile[tx][ty + j]);
}

// ---------------- transpose bf16 (R x C, ld) -> bf16 (C x R) ----------------
__global__ __launch_bounds__(256) void transpose_bf16(const u16* __restrict__ in, int ld_in,
                                                      u16* __restrict__ out, int R, int C) {
  __shared__ u16 tile[32][33];
  int c0 = blockIdx.x * 32, r0 = blockIdx.y * 32;
  int tx = threadIdx.x, ty = threadIdx.y;
  for (int j = 0; j < 32; j += 8)
    tile[ty + j][tx] = in[(size_t)(r0 + ty + j) * ld_in + c0 + tx];
  __syncthreads();
  for (int j = 0; j < 32; j += 8)
    out[(size_t)(c0 + ty + j) * R + r0 + tx] = tile[tx][ty + j];
}

// ---------------- GEMM v3 (unchanged from round 7) ----------------
template <bool F32OUT, bool DO_ROPE>
__global__ __launch_bounds__(512, 4) void gemm_bt(const u16* __restrict__ A,
                                                  const u16* __restrict__ BT,
                                                  void* __restrict__ Cout,
                                                  int M, int N, int K,
                                                  const float* __restrict__ cosT,
                                                  const float* __restrict__ sinT) {
  const int bn = blockIdx.x * 128, bm = blockIdx.y * 128;
  const int tid = threadIdx.x;
  const int wid = tid >> 6, lane = tid & 63;
  const int wr = wid >> 2, wc = wid & 3;
  const int lrow = lane & 15, g = lane >> 4;

  __shared__ __align__(16) u16 As[2][128 * 64];
  __shared__ __align__(16) u16 Bs[2][128 * 64];

  const int srow = tid >> 3;
  const int cswz = (((tid & 7) ^ (srow & 7)) << 3);
  const u16* a_src = A + (size_t)(bm + srow) * K + cswz;
  const u16* b_src = BT + (size_t)(bn + srow) * K + cswz;

  const int swz16 = (lrow & 7) << 3;
  const int colsw0 = (g * 8) ^ swz16;
  const int colsw1 = (32 + g * 8) ^ swz16;

#define STAGE(buf, k0)                                                        \
  do {                                                                        \
    const u16* ap = a_src + (k0);                                             \
    const u16* bp = b_src + (k0);                                             \
    u16* ad = &As[buf][0] + tid * 8;                                          \
    u16* bd = &Bs[buf][0] + tid * 8;                                          \
    _Pragma("unroll") for (int p = 0; p < 2; ++p) {                           \
      gload_lds16(ap + (size_t)p * 64 * K, ad + p * 4096);                    \
      gload_lds16(bp + (size_t)p * 64 * K, bd + p * 4096);                    \
    }                                                                         \
  } while (0)

  f32x4 acc[4][2] = {};

  const int nt = K >> 6;
  STAGE(0, 0);
  int cur = 0;
  for (int t = 0; t < nt; ++t) {
    if (t + 1 < nt) {
      STAGE(cur ^ 1, (t + 1) * 64);
      asm volatile("s_waitcnt vmcnt(4)" ::: "memory");
    } else {
      asm volatile("s_waitcnt vmcnt(0)" ::: "memory");
    }
    __builtin_amdgcn_s_barrier();
    asm volatile("" ::: "memory");

    bf16x8 af[4][2], bfr[2][2];
#pragma unroll
    for (int m = 0; m < 4; ++m) {
      int row = wr * 64 + m * 16 + lrow;
      af[m][0] = *(const bf16x8*)&As[cur][row * 64 + colsw0];
      af[m][1] = *(const bf16x8*)&As[cur][row * 64 + colsw1];
    }
#pragma unroll
    for (int n = 0; n < 2; ++n) {
      int row = wc * 32 + n * 16 + lrow;
      bfr[n][0] = *(const bf16x8*)&Bs[cur][row * 64 + colsw0];
      bfr[n][1] = *(const bf16x8*)&Bs[cur][row * 64 + colsw1];
    }
#pragma unroll
    for (int ks = 0; ks < 2; ++ks)
#pragma unroll
      for (int m = 0; m < 4; ++m)
#pragma unroll
        for (int n = 0; n < 2; ++n)
          acc[m][n] =
              __builtin_amdgcn_mfma_f32_16x16x32_bf16(af[m][ks], bfr[n][ks], acc[m][n], 0, 0, 0);

    asm volatile("" ::: "memory");
    __builtin_amdgcn_s_barrier();
    cur ^= 1;
  }
#undef STAGE

#pragma unroll
  for (int m = 0; m < 4; ++m) {
    int row0 = bm + wr * 64 + m * 16 + (g << 2);
#pragma unroll
    for (int n = 0; n < 2; ++n) {
      int col = bn + wc * 32 + n * 16 + lrow;
      f32x4 v = acc[m][n];
      if constexpr (DO_ROPE) {
        if (bn < 2304) {
          int i = (col & 63) >> 1;
          float sg = (col & 1) ? 1.f : -1.f;
#pragma unroll
          for (int r = 0; r < 4; ++r) {
            float pv = __shfl_xor(v[r], 1, 64);
            float c = cosT[(row0 + r) * 32 + i];
            float s = sinT[(row0 + r) * 32 + i];
            v[r] = v[r] * c + pv * s * sg;
          }
        }
      }
#pragma unroll
      for (int r = 0; r < 4; ++r) {
        if constexpr (F32OUT)
          ((float*)Cout)[(size_t)(row0 + r) * N + col] = v[r];
        else
          ((u16*)Cout)[(size_t)(row0 + r) * N + col] = f2bf(v[r]);
      }
    }
  }
}

// ---------------- flash attention v6: balanced pair-split ----------------
// grid (32, 16): pair p = by&7, piece = by>>3. a = p (short q-tile), b = 15-p.
// piece0: tile a fully (p+1 t-iters) + chunk [0,7-p) of tile b = 8 iters.
// piece1: chunk [7-p, 16-p) of tile b = 9 iters.
// t indexes 128-key groups; wave-half processes kb=(2t+half)*64.
// Tile-b chunks write unnormalized partials (bf16 acc + f32 m,l) -> merge kernel.
__global__ __launch_bounds__(512) void attn_kernel(const u16* __restrict__ QKV,
                                                   const u16* __restrict__ VT,
                                                   u16* __restrict__ attn_out,
                                                   u16* __restrict__ Ppart) {
  const int h = blockIdx.x;
  const int p = blockIdx.y & 7, piece = blockIdx.y >> 3;
  const int tid = threadIdx.x, w = tid >> 6, lane = tid & 63;
  const int wq4 = w & 3, half = w >> 2;
  const int l31 = lane & 31, hh = lane >> 5;
  const int kh = h >> 3;

  __shared__ __align__(16) u16 smem[32768];

  const int srow8 = lane >> 3;
  const int scol = (((lane & 7) ^ srow8) << 3);
  const int ksw = (l31 & 7) << 3;
  const float SC = 0.125f * 1.44269504088896f;

#define ASTAGE(buf, kb)                                                              \
  do {                                                                               \
    u16* kd = smem + (half * 2 + (buf)) * 4096 + (wq4 * 8) * 64 + lane * 8;          \
    u16* vd = smem + 16384 + (half * 2 + (buf)) * 4096 + (wq4 * 8) * 64 + lane * 8;  \
    _Pragma("unroll") for (int pp = 0; pp < 2; ++pp) {                               \
      int rr = pp * 32 + wq4 * 8 + srow8;                                            \
      gload_lds16(QKV + (size_t)((kb) + rr) * 2560 + 2048 + kh * 64 + scol,          \
                  kd + pp * 2048);                                                   \
      gload_lds16(VT + (size_t)(kh * 64 + rr) * 2048 + (kb) + scol, vd + pp * 2048); \
    }                                                                                \
  } while (0)

  auto do_phase = [&](int qb, int t0, int t1, bool finalW, int pidx) {
    const int q0w = qb * 128 + wq4 * 32;
    const int qg = q0w + l31;

    __syncthreads();  // protect smem from previous phase's merge reads

    bf16x8 qf[4];
    {
      size_t base = (size_t)qg * 2560 + h * 64 + hh * 8;
#pragma unroll
      for (int ks = 0; ks < 4; ++ks) qf[ks] = *(const bf16x8*)&QKV[base + ks * 16];
    }

    f32x16 acc0 = {}, acc1 = {};
    float mrun = -1e30f, lrun = 0.f;

    ASTAGE(0, (2 * t0 + half) * 64);
    int cur = 0;

    for (int t = t0; t < t1; ++t) {
      const int kb = (2 * t + half) * 64;
      if (t + 1 < t1) {
        ASTAGE(cur ^ 1, kb + 128);
        asm volatile("s_waitcnt vmcnt(4)" ::: "memory");
      } else {
        asm volatile("s_waitcnt vmcnt(0)" ::: "memory");
      }
      __builtin_amdgcn_s_barrier();
      asm volatile("" ::: "memory");

      if (kb <= q0w + 31) {
        const u16* Kc = smem + (half * 2 + cur) * 4096;
        const u16* Vc = smem + 16384 + (half * 2 + cur) * 4096;

        f32x16 sc0 = {}, sc1 = {};
        __builtin_amdgcn_s_setprio(1);
#pragma unroll
        for (int ks = 0; ks < 4; ++ks) {
          int c = (ks * 16 + hh * 8) ^ ksw;
          bf16x8 kf0 = *(const bf16x8*)&Kc[l31 * 64 + c];
          bf16x8 kf1 = *(const bf16x8*)&Kc[(32 + l31) * 64 + c];
          sc0 = __builtin_amdgcn_mfma_f32_32x32x16_bf16(kf0, qf[ks], sc0, 0, 0, 0);
          sc1 = __builtin_amdgcn_mfma_f32_32x32x16_bf16(kf1, qf[ks], sc1, 0, 0, 0);
        }
        __builtin_amdgcn_s_setprio(0);

        if (kb + 63 > q0w) {
#pragma unroll
          for (int r = 0; r < 16; ++r) {
            int keyoff = (r & 3) + 8 * (r >> 2) + 4 * hh;
            if (kb + keyoff > qg) sc0[r] = -1e5f;
            if (kb + 32 + keyoff > qg) sc1[r] = -1e5f;
          }
        }

        float m8[8];
#pragma unroll
        for (int i = 0; i < 8; ++i)
          m8[i] = fmaxf(fmaxf(sc0[i], sc0[i + 8]), fmaxf(sc1[i], sc1[i + 8]));
#pragma unroll
        for (int st = 4; st >= 1; st >>= 1)
#pragma unroll
          for (int i = 0; i < st; ++i) m8[i] = fmaxf(m8[i], m8[i + st]);
        float mx = fmaxf(m8[0], __shfl_xor(m8[0], 32, 64));
        float mxs = mx * SC;

        if (__any(mxs > mrun + 8.f)) {
          float nm = fmaxf(mrun, mxs);
          float fs = fexp2(mrun - nm);
          mrun = nm;
          lrun *= fs;
#pragma unroll
          for (int i = 0; i < 16; ++i) { acc0[i] *= fs; acc1[i] *= fs; }
        }

        float p0[16], p1[16];
        const float nmn = -mrun;
#pragma unroll
        for (int i = 0; i < 16; ++i) {
          p0[i] = fexp2(__builtin_fmaf(sc0[i], SC, nmn));
          p1[i] = fexp2(__builtin_fmaf(sc1[i], SC, nmn));
        }
        float s8[8];
#pragma unroll
        for (int i = 0; i < 8; ++i) s8[i] = (p0[i] + p0[i + 8]) + (p1[i] + p1[i + 8]);
#pragma unroll
        for (int st = 4; st >= 1; st >>= 1)
#pragma unroll
          for (int i = 0; i < st; ++i) s8[i] += s8[i + st];
        lrun += s8[0] + __shfl_xor(s8[0], 32, 64);

        bf16x8 pf[4];
#pragma unroll
        for (int tt = 0; tt < 2; ++tt) {
          const float* pp = tt ? p1 : p0;
          unsigned wd[8];
#pragma unroll
          for (int j = 0; j < 8; ++j) wd[j] = cvt_pk_bf16(pp[2 * j], pp[2 * j + 1]);
          uv2 sA = __builtin_amdgcn_permlane32_swap(wd[0], wd[2], false, false);
          uv2 sB = __builtin_amdgcn_permlane32_swap(wd[1], wd[3], false, false);
          uv2 sC = __builtin_amdgcn_permlane32_swap(wd[4], wd[6], false, false);
          uv2 sD = __builtin_amdgcn_permlane32_swap(wd[5], wd[7], false, false);
          u32x4 f0 = {sA[0], sB[0], sA[1], sB[1]};
          u32x4 f1 = {sC[0], sD[0], sC[1], sD[1]};
          pf[tt * 2 + 0] = __builtin_bit_cast(bf16x8, f0);
          pf[tt * 2 + 1] = __builtin_bit_cast(bf16x8, f1);
        }

        __builtin_amdgcn_s_setprio(1);
#pragma unroll
        for (int ks = 0; ks < 4; ++ks) {
          int c = (ks * 16 + hh * 8) ^ ksw;
          bf16x8 vf0 = *(const bf16x8*)&Vc[l31 * 64 + c];
          bf16x8 vf1 = *(const bf16x8*)&Vc[(32 + l31) * 64 + c];
          acc0 = __builtin_amdgcn_mfma_f32_32x32x16_bf16(vf0, pf[ks], acc0, 0, 0, 0);
          acc1 = __builtin_amdgcn_mfma_f32_32x32x16_bf16(vf1, pf[ks], acc1, 0, 0, 0);
        }
        __builtin_amdgcn_s_setprio(0);
      }

      asm volatile("" ::: "memory");
      __builtin_amdgcn_s_barrier();
      cur ^= 1;
    }

    // merge kv-halves via smem
    float* MRG = (float*)smem;
    float4* CH = (float4*)smem;
    if (half == 1) {
#pragma unroll
      for (int c = 0; c < 4; ++c) {
        float4 v0 = {acc0[4 * c + 0], acc0[4 * c + 1], acc0[4 * c + 2], acc0[4 * c + 3]};
        float4 v1 = {acc1[4 * c + 0], acc1[4 * c + 1], acc1[4 * c + 2], acc1[4 * c + 3]};
        CH[(wq4 * 8 + c) * 64 + lane] = v0;
        CH[(wq4 * 8 + 4 + c) * 64 + lane] = v1;
      }
      MRG[8192 + wq4 * 128 + lane * 2 + 0] = mrun;
      MRG[8192 + wq4 * 128 + lane * 2 + 1] = lrun;
    }
    __syncthreads();
    if (half == 0) {
      float m1 = MRG[8192 + wq4 * 128 + lane * 2 + 0];
      float l1 = MRG[8192 + wq4 * 128 + lane * 2 + 1];
      float m = fmaxf(mrun, m1);
      float f0 = fexp2(mrun - m), f1 = fexp2(m1 - m);
      float a, b;
      u16* obase;
      size_t ostride;
      if (finalW) {
        float inv = 1.f / (lrun * f0 + l1 * f1);
        a = f0 * inv; b = f1 * inv;
        obase = attn_out + (size_t)qg * 2048 + h * 64;
        ostride = 1;
      } else {
        a = f0; b = f1;
        u16* pb = Ppart + (size_t)((h * 8 + p) * 2 + pidx) * 8704;
        obase = pb + (wq4 * 32 + l31) * 64;
        ostride = 1;
        if (hh == 0) {
          float* pm = (float*)(pb + 8192);
          pm[wq4 * 32 + l31] = m;
          pm[128 + wq4 * 32 + l31] = lrun * f0 + l1 * f1;
        }
      }
#pragma unroll
      for (int c = 0; c < 4; ++c) {
        float4 r0 = CH[(wq4 * 8 + c) * 64 + lane];
        float4 r1 = CH[(wq4 * 8 + 4 + c) * 64 + lane];
        u16x4 o0, o1;
        o0[0] = f2bf(acc0[4 * c + 0] * a + r0.x * b);
        o0[1] = f2bf(acc0[4 * c + 1] * a + r0.y * b);
        o0[2] = f2bf(acc0[4 * c + 2] * a + r0.z * b);
        o0[3] = f2bf(acc0[4 * c + 3] * a + r0.w * b);
        o1[0] = f2bf(acc1[4 * c + 0] * a + r1.x * b);
        o1[1] = f2bf(acc1[4 * c + 1] * a + r1.y * b);
        o1[2] = f2bf(acc1[4 * c + 2] * a + r1.z * b);
        o1[3] = f2bf(acc1[4 * c + 3] * a + r1.w * b);
        *(u16x4*)&obase[8 * c + 4 * hh] = o0;
        *(u16x4*)&obase[32 + 8 * c + 4 * hh] = o1;
      }
    }
  };

  if (piece == 0) {
    do_phase(p, 0, p + 1, true, -1);
    if (p < 7) do_phase(15 - p, 0, 7 - p, false, 0);
  } else {
    const int t0 = 7 - p;
    do_phase(15 - p, t0, 16 - p, t0 == 0, 1);
  }
#undef ASTAGE
}

// ---------------- merge partials for tile b of pairs 0..6 ----------------
__global__ __launch_bounds__(256) void attn_merge(const u16* __restrict__ Ppart,
                                                  u16* __restrict__ attn_out) {
  const int h = blockIdx.x, p = blockIdx.y;  // p in 0..6
  const int b = 15 - p;
  const int tid = threadIdx.x;
  const int r = tid >> 1, dh = tid & 1;
  const u16* b0 = Ppart + (size_t)((h * 8 + p) * 2 + 0) * 8704;
  const u16* b1 = Ppart + (size_t)((h * 8 + p) * 2 + 1) * 8704;
  const float* ml0 = (const float*)(b0 + 8192);
  const float* ml1 = (const float*)(b1 + 8192);
  float m0 = ml0[r], l0 = ml0[128 + r];
  float m1 = ml1[r], l1 = ml1[128 + r];
  float m = fmaxf(m0, m1);
  float f0 = fexp2(m0 - m), f1 = fexp2(m1 - m);
  float inv = 1.f / (l0 * f0 + l1 * f1);
  float a = f0 * inv, bs = f1 * inv;
  const u16* a0 = b0 + r * 64 + dh * 32;
  const u16* a1 = b1 + r * 64 + dh * 32;
  u16* out = attn_out + (size_t)(b * 128 + r) * 2048 + h * 64 + dh * 32;
#pragma unroll
  for (int j = 0; j < 8; ++j) {
    u16x4 v0 = *(const u16x4*)&a0[j * 4];
    u16x4 v1 = *(const u16x4*)&a1[j * 4];
    u16x4 o;
#pragma unroll
    for (int e = 0; e < 4; ++e) o[e] = f2bf(bf2f(v0[e]) * a + bf2f(v1[e]) * bs);
    *(u16x4*)&out[j * 4] = o;
  }
}

extern "C" void kernel_launch(void* const* d_in, const int* in_sizes, int n_in,
                              void* d_out, int out_size, void* d_ws, size_t ws_size,
                              hipStream_t stream) {
  const float* x = (const float*)d_in[0];
  const float* fcos = (const float*)d_in[1];
  const float* fsin = (const float*)d_in[2];
  const float* wq = (const float*)d_in[4];
  const float* wk = (const float*)d_in[5];
  const float* wv = (const float*)d_in[6];
  const float* wo = (const float*)d_in[7];

  char* ws = (char*)d_ws;
  u16* xb    = (u16*)(ws);                    // 8 MB (reused as attn later)
  u16* wqkvT = (u16*)(ws + (8u << 20));       // 10 MB (reused as attn partials)
  u16* woT   = (u16*)(ws + (18u << 20));      // 8 MB
  u16* QKV   = (u16*)(ws + (26u << 20));      // 10 MB
  u16* VT    = (u16*)(ws + (36u << 20));      // 1 MB
  u16* attn  = xb;
  u16* Ppart = wqkvT;  // dead after QKV GEMM

  dim3 tb32(32, 8);

  convert_f32_bf16<<<4096, 256, 0, stream>>>(x, xb, 2048 * 2048);
  transpose_wqkv<<<dim3(80, 64), tb32, 0, stream>>>(wq, wk, wv, wqkvT);
  transpose_f32_bf16<<<dim3(64, 64), tb32, 0, stream>>>(wo, woT, 2048, 2048);

  gemm_bt<false, true><<<dim3(20, 16), 512, 0, stream>>>(xb, wqkvT, QKV, 2048, 2560, 2048,
                                                         fcos, fsin);

  transpose_bf16<<<dim3(8, 64), tb32, 0, stream>>>(QKV + 2304, 2560, VT, 2048, 256);

  attn_kernel<<<dim3(32, 16), 512, 0, stream>>>(QKV, VT, attn, Ppart);
  attn_merge<<<dim3(32, 7), 256, 0, stream>>>(Ppart, attn);

  gemm_bt<true, false><<<dim3(16, 16), 512, 0, stream>>>(attn, woT, d_out, 2048, 2048, 2048,
                                                         nullptr, nullptr);
}

// Round 9
// 124.836 us; speedup vs baseline: 1.0772x; 1.0772x over previous
//
#include <hip/hip_runtime.h>

typedef unsigned short u16;
typedef __attribute__((ext_vector_type(4))) float f32x4;
typedef __attribute__((ext_vector_type(16))) float f32x16;
typedef __attribute__((ext_vector_type(8))) short bf16x8;
typedef __attribute__((ext_vector_type(4))) unsigned short u16x4;
typedef __attribute__((ext_vector_type(4))) unsigned u32x4;
typedef __attribute__((ext_vector_type(2))) unsigned uv2;

__device__ __forceinline__ u16 f2bf(float f) {
  unsigned u = __float_as_uint(f);
  u += 0x7FFFu + ((u >> 16) & 1u);
  return (u16)(u >> 16);
}
__device__ __forceinline__ float bf2f(u16 v) {
  return __uint_as_float(((unsigned)v) << 16);
}

__device__ __forceinline__ void gload_lds16(const u16* g, u16* l) {
  __builtin_amdgcn_global_load_lds((const __attribute__((address_space(1))) void*)g,
                                   (__attribute__((address_space(3))) void*)l, 16, 0, 0);
}

__device__ __forceinline__ unsigned cvt_pk_bf16(float lo, float hi) {
  unsigned r;
  asm("v_cvt_pk_bf16_f32 %0, %1, %2" : "=v"(r) : "v"(lo), "v"(hi));
  return r;
}

__device__ __forceinline__ float fexp2(float x) {
#if __has_builtin(__builtin_amdgcn_exp2f)
  return __builtin_amdgcn_exp2f(x);
#else
  return __expf(x * 0.6931471805599453f);
#endif
}

// ---------------- convert fp32 -> bf16 ----------------
__global__ __launch_bounds__(256) void convert_f32_bf16(const float* __restrict__ in,
                                                        u16* __restrict__ out, int n) {
  int i = (blockIdx.x * 256 + threadIdx.x) * 4;
  if (i >= n) return;
  float4 v = *(const float4*)&in[i];
  out[i + 0] = f2bf(v.x);
  out[i + 1] = f2bf(v.y);
  out[i + 2] = f2bf(v.z);
  out[i + 3] = f2bf(v.w);
}

// ---------------- transpose fp32 (R x C) -> bf16 (C x R) ----------------
__global__ __launch_bounds__(256) void transpose_f32_bf16(const float* __restrict__ in,
                                                          u16* __restrict__ out,
                                                          int R, int C) {
  __shared__ float tile[32][33];
  int c0 = blockIdx.x * 32, r0 = blockIdx.y * 32;
  int tx = threadIdx.x, ty = threadIdx.y;
  for (int j = 0; j < 32; j += 8)
    tile[ty + j][tx] = in[(size_t)(r0 + ty + j) * C + c0 + tx];
  __syncthreads();
  for (int j = 0; j < 32; j += 8)
    out[(size_t)(c0 + ty + j) * R + r0 + tx] = f2bf(tile[tx][ty + j]);
}

// ---------------- fused wq/wk/wv transpose -> wqkvT [2560][2048] ----------------
__global__ __launch_bounds__(256) void transpose_wqkv(const float* __restrict__ wq,
                                                      const float* __restrict__ wk,
                                                      const float* __restrict__ wv,
                                                      u16* __restrict__ out) {
  __shared__ float tile[32][33];
  int bx = blockIdx.x, r0 = blockIdx.y * 32;
  const float* src;
  int C, cc0;
  if (bx < 64) { src = wq; C = 2048; cc0 = bx * 32; }
  else if (bx < 72) { src = wk; C = 256; cc0 = (bx - 64) * 32; }
  else { src = wv; C = 256; cc0 = (bx - 72) * 32; }
  int tx = threadIdx.x, ty = threadIdx.y;
  for (int j = 0; j < 32; j += 8)
    tile[ty + j][tx] = src[(size_t)(r0 + ty + j) * C + cc0 + tx];
  __syncthreads();
  for (int j = 0; j < 32; j += 8)
    out[(size_t)(bx * 32 + ty + j) * 2048 + r0 + tx] = f2bf(tile[tx][ty + j]);
}

// ---------------- transpose bf16 (R x C, ld) -> bf16 (C x R) ----------------
__global__ __launch_bounds__(256) void transpose_bf16(const u16* __restrict__ in, int ld_in,
                                                      u16* __restrict__ out, int R, int C) {
  __shared__ u16 tile[32][33];
  int c0 = blockIdx.x * 32, r0 = blockIdx.y * 32;
  int tx = threadIdx.x, ty = threadIdx.y;
  for (int j = 0; j < 32; j += 8)
    tile[ty + j][tx] = in[(size_t)(r0 + ty + j) * ld_in + c0 + tx];
  __syncthreads();
  for (int j = 0; j < 32; j += 8)
    out[(size_t)(c0 + ty + j) * R + r0 + tx] = tile[tx][ty + j];
}

// ---------------- GEMM v3 (round 7, unchanged) ----------------
template <bool F32OUT, bool DO_ROPE>
__global__ __launch_bounds__(512, 4) void gemm_bt(const u16* __restrict__ A,
                                                  const u16* __restrict__ BT,
                                                  void* __restrict__ Cout,
                                                  int M, int N, int K,
                                                  const float* __restrict__ cosT,
                                                  const float* __restrict__ sinT) {
  const int bn = blockIdx.x * 128, bm = blockIdx.y * 128;
  const int tid = threadIdx.x;
  const int wid = tid >> 6, lane = tid & 63;
  const int wr = wid >> 2, wc = wid & 3;
  const int lrow = lane & 15, g = lane >> 4;

  __shared__ __align__(16) u16 As[2][128 * 64];
  __shared__ __align__(16) u16 Bs[2][128 * 64];

  const int srow = tid >> 3;
  const int cswz = (((tid & 7) ^ (srow & 7)) << 3);
  const u16* a_src = A + (size_t)(bm + srow) * K + cswz;
  const u16* b_src = BT + (size_t)(bn + srow) * K + cswz;

  const int swz16 = (lrow & 7) << 3;
  const int colsw0 = (g * 8) ^ swz16;
  const int colsw1 = (32 + g * 8) ^ swz16;

#define STAGE(buf, k0)                                                        \
  do {                                                                        \
    const u16* ap = a_src + (k0);                                             \
    const u16* bp = b_src + (k0);                                             \
    u16* ad = &As[buf][0] + tid * 8;                                          \
    u16* bd = &Bs[buf][0] + tid * 8;                                          \
    _Pragma("unroll") for (int p = 0; p < 2; ++p) {                           \
      gload_lds16(ap + (size_t)p * 64 * K, ad + p * 4096);                    \
      gload_lds16(bp + (size_t)p * 64 * K, bd + p * 4096);                    \
    }                                                                         \
  } while (0)

  f32x4 acc[4][2] = {};

  const int nt = K >> 6;
  STAGE(0, 0);
  int cur = 0;
  for (int t = 0; t < nt; ++t) {
    if (t + 1 < nt) {
      STAGE(cur ^ 1, (t + 1) * 64);
      asm volatile("s_waitcnt vmcnt(4)" ::: "memory");
    } else {
      asm volatile("s_waitcnt vmcnt(0)" ::: "memory");
    }
    __builtin_amdgcn_s_barrier();
    asm volatile("" ::: "memory");

    bf16x8 af[4][2], bfr[2][2];
#pragma unroll
    for (int m = 0; m < 4; ++m) {
      int row = wr * 64 + m * 16 + lrow;
      af[m][0] = *(const bf16x8*)&As[cur][row * 64 + colsw0];
      af[m][1] = *(const bf16x8*)&As[cur][row * 64 + colsw1];
    }
#pragma unroll
    for (int n = 0; n < 2; ++n) {
      int row = wc * 32 + n * 16 + lrow;
      bfr[n][0] = *(const bf16x8*)&Bs[cur][row * 64 + colsw0];
      bfr[n][1] = *(const bf16x8*)&Bs[cur][row * 64 + colsw1];
    }
#pragma unroll
    for (int ks = 0; ks < 2; ++ks)
#pragma unroll
      for (int m = 0; m < 4; ++m)
#pragma unroll
        for (int n = 0; n < 2; ++n)
          acc[m][n] =
              __builtin_amdgcn_mfma_f32_16x16x32_bf16(af[m][ks], bfr[n][ks], acc[m][n], 0, 0, 0);

    asm volatile("" ::: "memory");
    __builtin_amdgcn_s_barrier();
    cur ^= 1;
  }
#undef STAGE

#pragma unroll
  for (int m = 0; m < 4; ++m) {
    int row0 = bm + wr * 64 + m * 16 + (g << 2);
#pragma unroll
    for (int n = 0; n < 2; ++n) {
      int col = bn + wc * 32 + n * 16 + lrow;
      f32x4 v = acc[m][n];
      if constexpr (DO_ROPE) {
        if (bn < 2304) {
          int i = (col & 63) >> 1;
          float sg = (col & 1) ? 1.f : -1.f;
#pragma unroll
          for (int r = 0; r < 4; ++r) {
            float pv = __shfl_xor(v[r], 1, 64);
            float c = cosT[(row0 + r) * 32 + i];
            float s = sinT[(row0 + r) * 32 + i];
            v[r] = v[r] * c + pv * s * sg;
          }
        }
      }
#pragma unroll
      for (int r = 0; r < 4; ++r) {
        if constexpr (F32OUT)
          ((float*)Cout)[(size_t)(row0 + r) * N + col] = v[r];
        else
          ((u16*)Cout)[(size_t)(row0 + r) * N + col] = f2bf(v[r]);
      }
    }
  }
}

// ---------------- flash attention v7: v5 body + CU-balanced qb pairing ----------------
// grid (32,16), 512 threads, 2 blocks/CU. Same-CU pairs are (id, id+256) i.e.
// (x,y)&(x,y+8); qb map y<8 ? y : 23-y makes every pair sum to 17 t-iters.
__global__ __launch_bounds__(512) void attn_kernel(const u16* __restrict__ QKV,
                                                   const u16* __restrict__ VT,
                                                   u16* __restrict__ attn_out) {
  const int h = blockIdx.x;
  const int yy = (int)blockIdx.y;
  const int qb = (yy < 8) ? yy : 23 - yy;  // pair-sum = 15 per CU
  const int tid = threadIdx.x, w = tid >> 6, lane = tid & 63;
  const int wq4 = w & 3, half = w >> 2;
  const int l31 = lane & 31, hh = lane >> 5;
  const int kh = h >> 3;
  const int q0w = qb * 128 + wq4 * 32;
  const int qg = q0w + l31;

  __shared__ __align__(16) u16 smem[32768];

  const int srow8 = lane >> 3;
  const int scol = (((lane & 7) ^ srow8) << 3);

#define ASTAGE(buf, kb)                                                              \
  do {                                                                               \
    u16* kd = smem + (half * 2 + (buf)) * 4096 + (wq4 * 8) * 64 + lane * 8;          \
    u16* vd = smem + 16384 + (half * 2 + (buf)) * 4096 + (wq4 * 8) * 64 + lane * 8;  \
    _Pragma("unroll") for (int p = 0; p < 2; ++p) {                                  \
      int rr = p * 32 + wq4 * 8 + srow8;                                             \
      gload_lds16(QKV + (size_t)((kb) + rr) * 2560 + 2048 + kh * 64 + scol,          \
                  kd + p * 2048);                                                    \
      gload_lds16(VT + (size_t)(kh * 64 + rr) * 2048 + (kb) + scol, vd + p * 2048);  \
    }                                                                                \
  } while (0)

  bf16x8 qf[4];
  {
    size_t base = (size_t)qg * 2560 + h * 64 + hh * 8;
#pragma unroll
    for (int ks = 0; ks < 4; ++ks) qf[ks] = *(const bf16x8*)&QKV[base + ks * 16];
  }

  const int ksw = (l31 & 7) << 3;

  f32x16 acc0 = {}, acc1 = {};
  float mrun = -1e30f, lrun = 0.f;
  const float SC = 0.125f * 1.44269504088896f;

  const int NT = qb + 1;
  ASTAGE(0, half * 64);
  int cur = 0;

  for (int t = 0; t < NT; ++t) {
    const int kb = (2 * t + half) * 64;
    if (t + 1 < NT) {
      ASTAGE(cur ^ 1, kb + 128);
      asm volatile("s_waitcnt vmcnt(4)" ::: "memory");
    } else {
      asm volatile("s_waitcnt vmcnt(0)" ::: "memory");
    }
    __builtin_amdgcn_s_barrier();
    asm volatile("" ::: "memory");

    if (kb <= q0w + 31) {
      const u16* Kc = smem + (half * 2 + cur) * 4096;
      const u16* Vc = smem + 16384 + (half * 2 + cur) * 4096;

      f32x16 sc0 = {}, sc1 = {};
      __builtin_amdgcn_s_setprio(1);
#pragma unroll
      for (int ks = 0; ks < 4; ++ks) {
        int c = (ks * 16 + hh * 8) ^ ksw;
        bf16x8 kf0 = *(const bf16x8*)&Kc[l31 * 64 + c];
        bf16x8 kf1 = *(const bf16x8*)&Kc[(32 + l31) * 64 + c];
        sc0 = __builtin_amdgcn_mfma_f32_32x32x16_bf16(kf0, qf[ks], sc0, 0, 0, 0);
        sc1 = __builtin_amdgcn_mfma_f32_32x32x16_bf16(kf1, qf[ks], sc1, 0, 0, 0);
      }
      __builtin_amdgcn_s_setprio(0);

      if (kb + 63 > q0w) {
#pragma unroll
        for (int r = 0; r < 16; ++r) {
          int keyoff = (r & 3) + 8 * (r >> 2) + 4 * hh;
          if (kb + keyoff > qg) sc0[r] = -1e5f;
          if (kb + 32 + keyoff > qg) sc1[r] = -1e5f;
        }
      }

      float m8[8];
#pragma unroll
      for (int i = 0; i < 8; ++i)
        m8[i] = fmaxf(fmaxf(sc0[i], sc0[i + 8]), fmaxf(sc1[i], sc1[i + 8]));
#pragma unroll
      for (int st = 4; st >= 1; st >>= 1)
#pragma unroll
        for (int i = 0; i < st; ++i) m8[i] = fmaxf(m8[i], m8[i + st]);
      float mx = fmaxf(m8[0], __shfl_xor(m8[0], 32, 64));
      float mxs = mx * SC;

      if (__any(mxs > mrun + 8.f)) {
        float nm = fmaxf(mrun, mxs);
        float fs = fexp2(mrun - nm);
        mrun = nm;
        lrun *= fs;
#pragma unroll
        for (int i = 0; i < 16; ++i) { acc0[i] *= fs; acc1[i] *= fs; }
      }

      float p0[16], p1[16];
      const float nmn = -mrun;
#pragma unroll
      for (int i = 0; i < 16; ++i) {
        p0[i] = fexp2(__builtin_fmaf(sc0[i], SC, nmn));
        p1[i] = fexp2(__builtin_fmaf(sc1[i], SC, nmn));
      }
      float s8[8];
#pragma unroll
      for (int i = 0; i < 8; ++i) s8[i] = (p0[i] + p0[i + 8]) + (p1[i] + p1[i + 8]);
#pragma unroll
      for (int st = 4; st >= 1; st >>= 1)
#pragma unroll
        for (int i = 0; i < st; ++i) s8[i] += s8[i + st];
      lrun += s8[0] + __shfl_xor(s8[0], 32, 64);

      bf16x8 pf[4];
#pragma unroll
      for (int tt = 0; tt < 2; ++tt) {
        const float* pp = tt ? p1 : p0;
        unsigned wd[8];
#pragma unroll
        for (int j = 0; j < 8; ++j) wd[j] = cvt_pk_bf16(pp[2 * j], pp[2 * j + 1]);
        uv2 sA = __builtin_amdgcn_permlane32_swap(wd[0], wd[2], false, false);
        uv2 sB = __builtin_amdgcn_permlane32_swap(wd[1], wd[3], false, false);
        uv2 sC = __builtin_amdgcn_permlane32_swap(wd[4], wd[6], false, false);
        uv2 sD = __builtin_amdgcn_permlane32_swap(wd[5], wd[7], false, false);
        u32x4 f0 = {sA[0], sB[0], sA[1], sB[1]};
        u32x4 f1 = {sC[0], sD[0], sC[1], sD[1]};
        pf[tt * 2 + 0] = __builtin_bit_cast(bf16x8, f0);
        pf[tt * 2 + 1] = __builtin_bit_cast(bf16x8, f1);
      }

      __builtin_amdgcn_s_setprio(1);
#pragma unroll
      for (int ks = 0; ks < 4; ++ks) {
        int c = (ks * 16 + hh * 8) ^ ksw;
        bf16x8 vf0 = *(const bf16x8*)&Vc[l31 * 64 + c];
        bf16x8 vf1 = *(const bf16x8*)&Vc[(32 + l31) * 64 + c];
        acc0 = __builtin_amdgcn_mfma_f32_32x32x16_bf16(vf0, pf[ks], acc0, 0, 0, 0);
        acc1 = __builtin_amdgcn_mfma_f32_32x32x16_bf16(vf1, pf[ks], acc1, 0, 0, 0);
      }
      __builtin_amdgcn_s_setprio(0);
    }

    asm volatile("" ::: "memory");
    __builtin_amdgcn_s_barrier();
    cur ^= 1;
  }
#undef ASTAGE

  float* MRG = (float*)smem;
  float4* CH = (float4*)smem;
  if (half == 1) {
#pragma unroll
    for (int c = 0; c < 4; ++c) {
      float4 v0 = {acc0[4 * c + 0], acc0[4 * c + 1], acc0[4 * c + 2], acc0[4 * c + 3]};
      float4 v1 = {acc1[4 * c + 0], acc1[4 * c + 1], acc1[4 * c + 2], acc1[4 * c + 3]};
      CH[(wq4 * 8 + c) * 64 + lane] = v0;
      CH[(wq4 * 8 + 4 + c) * 64 + lane] = v1;
    }
    MRG[8192 + wq4 * 128 + lane * 2 + 0] = mrun;
    MRG[8192 + wq4 * 128 + lane * 2 + 1] = lrun;
  }
  __syncthreads();
  if (half == 0) {
    float m1 = MRG[8192 + wq4 * 128 + lane * 2 + 0];
    float l1 = MRG[8192 + wq4 * 128 + lane * 2 + 1];
    float m = fmaxf(mrun, m1);
    float f0 = fexp2(mrun - m), f1 = fexp2(m1 - m);
    float inv = 1.f / (lrun * f0 + l1 * f1);
    float a = f0 * inv, b = f1 * inv;
    size_t obase = (size_t)qg * 2048 + h * 64;
#pragma unroll
    for (int c = 0; c < 4; ++c) {
      float4 r0 = CH[(wq4 * 8 + c) * 64 + lane];
      float4 r1 = CH[(wq4 * 8 + 4 + c) * 64 + lane];
      u16x4 o0, o1;
      o0[0] = f2bf(acc0[4 * c + 0] * a + r0.x * b);
      o0[1] = f2bf(acc0[4 * c + 1] * a + r0.y * b);
      o0[2] = f2bf(acc0[4 * c + 2] * a + r0.z * b);
      o0[3] = f2bf(acc0[4 * c + 3] * a + r0.w * b);
      o1[0] = f2bf(acc1[4 * c + 0] * a + r1.x * b);
      o1[1] = f2bf(acc1[4 * c + 1] * a + r1.y * b);
      o1[2] = f2bf(acc1[4 * c + 2] * a + r1.z * b);
      o1[3] = f2bf(acc1[4 * c + 3] * a + r1.w * b);
      *(u16x4*)&attn_out[obase + 8 * c + 4 * hh] = o0;
      *(u16x4*)&attn_out[obase + 32 + 8 * c + 4 * hh] = o1;
    }
  }
}

extern "C" void kernel_launch(void* const* d_in, const int* in_sizes, int n_in,
                              void* d_out, int out_size, void* d_ws, size_t ws_size,
                              hipStream_t stream) {
  const float* x = (const float*)d_in[0];
  const float* fcos = (const float*)d_in[1];
  const float* fsin = (const float*)d_in[2];
  const float* wq = (const float*)d_in[4];
  const float* wk = (const float*)d_in[5];
  const float* wv = (const float*)d_in[6];
  const float* wo = (const float*)d_in[7];

  char* ws = (char*)d_ws;
  u16* xb    = (u16*)(ws);                    // 8 MB (reused as attn later)
  u16* wqkvT = (u16*)(ws + (8u << 20));       // 10 MB
  u16* woT   = (u16*)(ws + (18u << 20));      // 8 MB
  u16* QKV   = (u16*)(ws + (26u << 20));      // 10 MB
  u16* VT    = (u16*)(ws + (36u << 20));      // 1 MB
  u16* attn  = xb;

  dim3 tb32(32, 8);

  convert_f32_bf16<<<4096, 256, 0, stream>>>(x, xb, 2048 * 2048);
  transpose_wqkv<<<dim3(80, 64), tb32, 0, stream>>>(wq, wk, wv, wqkvT);
  transpose_f32_bf16<<<dim3(64, 64), tb32, 0, stream>>>(wo, woT, 2048, 2048);

  gemm_bt<false, true><<<dim3(20, 16), 512, 0, stream>>>(xb, wqkvT, QKV, 2048, 2560, 2048,
                                                         fcos, fsin);

  transpose_bf16<<<dim3(8, 64), tb32, 0, stream>>>(QKV + 2304, 2560, VT, 2048, 256);

  attn_kernel<<<dim3(32, 16), 512, 0, stream>>>(QKV, VT, attn);

  gemm_bt<true, false><<<dim3(16, 16), 512, 0, stream>>>(attn, woT, d_out, 2048, 2048, 2048,
                                                         nullptr, nullptr);
}

// Round 10
// 115.228 us; speedup vs baseline: 1.1671x; 1.0834x over previous
//
#include <hip/hip_runtime.h>

typedef unsigned short u16;
typedef __attribute__((ext_vector_type(4))) float f32x4;
typedef __attribute__((ext_vector_type(16))) float f32x16;
typedef __attribute__((ext_vector_type(8))) short bf16x8;
typedef __attribute__((ext_vector_type(4))) unsigned short u16x4;
typedef __attribute__((ext_vector_type(4))) unsigned u32x4;
typedef __attribute__((ext_vector_type(2))) unsigned uv2;

__device__ __forceinline__ u16 f2bf(float f) {
  unsigned u = __float_as_uint(f);
  u += 0x7FFFu + ((u >> 16) & 1u);
  return (u16)(u >> 16);
}
__device__ __forceinline__ float bf2f(u16 v) {
  return __uint_as_float(((unsigned)v) << 16);
}

__device__ __forceinline__ void gload_lds16(const u16* g, u16* l) {
  __builtin_amdgcn_global_load_lds((const __attribute__((address_space(1))) void*)g,
                                   (__attribute__((address_space(3))) void*)l, 16, 0, 0);
}

__device__ __forceinline__ unsigned cvt_pk_bf16(float lo, float hi) {
  unsigned r;
  asm("v_cvt_pk_bf16_f32 %0, %1, %2" : "=v"(r) : "v"(lo), "v"(hi));
  return r;
}

__device__ __forceinline__ float fexp2(float x) {
#if __has_builtin(__builtin_amdgcn_exp2f)
  return __builtin_amdgcn_exp2f(x);
#else
  return __expf(x * 0.6931471805599453f);
#endif
}

// ---------------- convert fp32 -> bf16 ----------------
__global__ __launch_bounds__(256) void convert_f32_bf16(const float* __restrict__ in,
                                                        u16* __restrict__ out, int n) {
  int i = (blockIdx.x * 256 + threadIdx.x) * 4;
  if (i >= n) return;
  float4 v = *(const float4*)&in[i];
  out[i + 0] = f2bf(v.x);
  out[i + 1] = f2bf(v.y);
  out[i + 2] = f2bf(v.z);
  out[i + 3] = f2bf(v.w);
}

// ---------------- transpose fp32 (R x C) -> bf16 (C x R) ----------------
__global__ __launch_bounds__(256) void transpose_f32_bf16(const float* __restrict__ in,
                                                          u16* __restrict__ out,
                                                          int R, int C) {
  __shared__ float tile[32][33];
  int c0 = blockIdx.x * 32, r0 = blockIdx.y * 32;
  int tx = threadIdx.x, ty = threadIdx.y;
  for (int j = 0; j < 32; j += 8)
    tile[ty + j][tx] = in[(size_t)(r0 + ty + j) * C + c0 + tx];
  __syncthreads();
  for (int j = 0; j < 32; j += 8)
    out[(size_t)(c0 + ty + j) * R + r0 + tx] = f2bf(tile[tx][ty + j]);
}

// ---------------- fused wq/wk/wv transpose -> wqkvT [2560][2048] ----------------
__global__ __launch_bounds__(256) void transpose_wqkv(const float* __restrict__ wq,
                                                      const float* __restrict__ wk,
                                                      const float* __restrict__ wv,
                                                      u16* __restrict__ out) {
  __shared__ float tile[32][33];
  int bx = blockIdx.x, r0 = blockIdx.y * 32;
  const float* src;
  int C, cc0;
  if (bx < 64) { src = wq; C = 2048; cc0 = bx * 32; }
  else if (bx < 72) { src = wk; C = 256; cc0 = (bx - 64) * 32; }
  else { src = wv; C = 256; cc0 = (bx - 72) * 32; }
  int tx = threadIdx.x, ty = threadIdx.y;
  for (int j = 0; j < 32; j += 8)
    tile[ty + j][tx] = src[(size_t)(r0 + ty + j) * C + cc0 + tx];
  __syncthreads();
  for (int j = 0; j < 32; j += 8)
    out[(size_t)(bx * 32 + ty + j) * 2048 + r0 + tx] = f2bf(tile[tx][ty + j]);
}

// ---------------- transpose bf16 (R x C, ld) -> bf16 (C x R) ----------------
__global__ __launch_bounds__(256) void transpose_bf16(const u16* __restrict__ in, int ld_in,
                                                      u16* __restrict__ out, int R, int C) {
  __shared__ u16 tile[32][33];
  int c0 = blockIdx.x * 32, r0 = blockIdx.y * 32;
  int tx = threadIdx.x, ty = threadIdx.y;
  for (int j = 0; j < 32; j += 8)
    tile[ty + j][tx] = in[(size_t)(r0 + ty + j) * ld_in + c0 + tx];
  __syncthreads();
  for (int j = 0; j < 32; j += 8)
    out[(size_t)(c0 + ty + j) * R + r0 + tx] = tile[tx][ty + j];
}

// ---------------- GEMM v4: 64x128 tile, 8 waves (2x4), BK=64, dbuf ----------------
// 3 gload_lds/thread/iter, source-col XOR swizzle, counted vmcnt(3).
// 48KB LDS + low VGPR -> 3 blocks/CU (launch_bounds 512,6).
template <bool F32OUT, bool DO_ROPE>
__global__ __launch_bounds__(512, 6) void gemm_bt(const u16* __restrict__ A,
                                                  const u16* __restrict__ BT,
                                                  void* __restrict__ Cout,
                                                  int M, int N, int K,
                                                  const float* __restrict__ cosT,
                                                  const float* __restrict__ sinT) {
  const int bn = blockIdx.x * 128, bm = blockIdx.y * 64;
  const int tid = threadIdx.x;
  const int wid = tid >> 6, lane = tid & 63;
  const int wr = wid >> 2, wc = wid & 3;  // 2 x 4 waves, wave tile 32x32
  const int lrow = lane & 15, g = lane >> 4;

  __shared__ __align__(16) u16 As[2][64 * 64];
  __shared__ __align__(16) u16 Bs[2][128 * 64];

  const int srow = tid >> 3;  // 0..63
  const int cswz = (((tid & 7) ^ (srow & 7)) << 3);
  const u16* a_src = A + (size_t)(bm + srow) * K + cswz;
  const u16* b_src = BT + (size_t)(bn + srow) * K + cswz;

  const int swz16 = (lrow & 7) << 3;
  const int colsw0 = (g * 8) ^ swz16;
  const int colsw1 = (32 + g * 8) ^ swz16;

#define STAGE(buf, k0)                                                        \
  do {                                                                        \
    gload_lds16(a_src + (k0), &As[buf][0] + tid * 8);                         \
    gload_lds16(b_src + (k0), &Bs[buf][0] + tid * 8);                         \
    gload_lds16(b_src + (size_t)64 * K + (k0), &Bs[buf][0] + 4096 + tid * 8); \
  } while (0)

  f32x4 acc[2][2] = {};

  const int nt = K >> 6;
  STAGE(0, 0);
  int cur = 0;
  for (int t = 0; t < nt; ++t) {
    if (t + 1 < nt) {
      STAGE(cur ^ 1, (t + 1) * 64);
      asm volatile("s_waitcnt vmcnt(3)" ::: "memory");
    } else {
      asm volatile("s_waitcnt vmcnt(0)" ::: "memory");
    }
    __builtin_amdgcn_s_barrier();
    asm volatile("" ::: "memory");

    bf16x8 af[2][2], bfr[2][2];
#pragma unroll
    for (int m = 0; m < 2; ++m) {
      int row = wr * 32 + m * 16 + lrow;
      af[m][0] = *(const bf16x8*)&As[cur][row * 64 + colsw0];
      af[m][1] = *(const bf16x8*)&As[cur][row * 64 + colsw1];
    }
#pragma unroll
    for (int n = 0; n < 2; ++n) {
      int row = wc * 32 + n * 16 + lrow;
      bfr[n][0] = *(const bf16x8*)&Bs[cur][row * 64 + colsw0];
      bfr[n][1] = *(const bf16x8*)&Bs[cur][row * 64 + colsw1];
    }
#pragma unroll
    for (int ks = 0; ks < 2; ++ks)
#pragma unroll
      for (int m = 0; m < 2; ++m)
#pragma unroll
        for (int n = 0; n < 2; ++n)
          acc[m][n] =
              __builtin_amdgcn_mfma_f32_16x16x32_bf16(af[m][ks], bfr[n][ks], acc[m][n], 0, 0, 0);

    asm volatile("" ::: "memory");
    __builtin_amdgcn_s_barrier();
    cur ^= 1;
  }
#undef STAGE

#pragma unroll
  for (int m = 0; m < 2; ++m) {
    int row0 = bm + wr * 32 + m * 16 + (g << 2);
#pragma unroll
    for (int n = 0; n < 2; ++n) {
      int col = bn + wc * 32 + n * 16 + lrow;
      f32x4 v = acc[m][n];
      if constexpr (DO_ROPE) {
        if (bn < 2304) {  // blockIdx.x < 18: Q/K columns (block-uniform)
          int i = (col & 63) >> 1;
          float sg = (col & 1) ? 1.f : -1.f;
#pragma unroll
          for (int r = 0; r < 4; ++r) {
            float pv = __shfl_xor(v[r], 1, 64);
            float c = cosT[(row0 + r) * 32 + i];
            float s = sinT[(row0 + r) * 32 + i];
            v[r] = v[r] * c + pv * s * sg;
          }
        }
      }
#pragma unroll
      for (int r = 0; r < 4; ++r) {
        if constexpr (F32OUT)
          ((float*)Cout)[(size_t)(row0 + r) * N + col] = v[r];
        else
          ((u16*)Cout)[(size_t)(row0 + r) * N + col] = f2bf(v[r]);
      }
    }
  }
}

// ---------------- flash attention v7 (unchanged): 32x32 MFMA + KV-split + CU pairing ----------------
__global__ __launch_bounds__(512) void attn_kernel(const u16* __restrict__ QKV,
                                                   const u16* __restrict__ VT,
                                                   u16* __restrict__ attn_out) {
  const int h = blockIdx.x;
  const int yy = (int)blockIdx.y;
  const int qb = (yy < 8) ? yy : 23 - yy;  // pair-sum = 15 per CU
  const int tid = threadIdx.x, w = tid >> 6, lane = tid & 63;
  const int wq4 = w & 3, half = w >> 2;
  const int l31 = lane & 31, hh = lane >> 5;
  const int kh = h >> 3;
  const int q0w = qb * 128 + wq4 * 32;
  const int qg = q0w + l31;

  __shared__ __align__(16) u16 smem[32768];

  const int srow8 = lane >> 3;
  const int scol = (((lane & 7) ^ srow8) << 3);

#define ASTAGE(buf, kb)                                                              \
  do {                                                                               \
    u16* kd = smem + (half * 2 + (buf)) * 4096 + (wq4 * 8) * 64 + lane * 8;          \
    u16* vd = smem + 16384 + (half * 2 + (buf)) * 4096 + (wq4 * 8) * 64 + lane * 8;  \
    _Pragma("unroll") for (int p = 0; p < 2; ++p) {                                  \
      int rr = p * 32 + wq4 * 8 + srow8;                                             \
      gload_lds16(QKV + (size_t)((kb) + rr) * 2560 + 2048 + kh * 64 + scol,          \
                  kd + p * 2048);                                                    \
      gload_lds16(VT + (size_t)(kh * 64 + rr) * 2048 + (kb) + scol, vd + p * 2048);  \
    }                                                                                \
  } while (0)

  bf16x8 qf[4];
  {
    size_t base = (size_t)qg * 2560 + h * 64 + hh * 8;
#pragma unroll
    for (int ks = 0; ks < 4; ++ks) qf[ks] = *(const bf16x8*)&QKV[base + ks * 16];
  }

  const int ksw = (l31 & 7) << 3;

  f32x16 acc0 = {}, acc1 = {};
  float mrun = -1e30f, lrun = 0.f;
  const float SC = 0.125f * 1.44269504088896f;

  const int NT = qb + 1;
  ASTAGE(0, half * 64);
  int cur = 0;

  for (int t = 0; t < NT; ++t) {
    const int kb = (2 * t + half) * 64;
    if (t + 1 < NT) {
      ASTAGE(cur ^ 1, kb + 128);
      asm volatile("s_waitcnt vmcnt(4)" ::: "memory");
    } else {
      asm volatile("s_waitcnt vmcnt(0)" ::: "memory");
    }
    __builtin_amdgcn_s_barrier();
    asm volatile("" ::: "memory");

    if (kb <= q0w + 31) {
      const u16* Kc = smem + (half * 2 + cur) * 4096;
      const u16* Vc = smem + 16384 + (half * 2 + cur) * 4096;

      f32x16 sc0 = {}, sc1 = {};
      __builtin_amdgcn_s_setprio(1);
#pragma unroll
      for (int ks = 0; ks < 4; ++ks) {
        int c = (ks * 16 + hh * 8) ^ ksw;
        bf16x8 kf0 = *(const bf16x8*)&Kc[l31 * 64 + c];
        bf16x8 kf1 = *(const bf16x8*)&Kc[(32 + l31) * 64 + c];
        sc0 = __builtin_amdgcn_mfma_f32_32x32x16_bf16(kf0, qf[ks], sc0, 0, 0, 0);
        sc1 = __builtin_amdgcn_mfma_f32_32x32x16_bf16(kf1, qf[ks], sc1, 0, 0, 0);
      }
      __builtin_amdgcn_s_setprio(0);

      if (kb + 63 > q0w) {
#pragma unroll
        for (int r = 0; r < 16; ++r) {
          int keyoff = (r & 3) + 8 * (r >> 2) + 4 * hh;
          if (kb + keyoff > qg) sc0[r] = -1e5f;
          if (kb + 32 + keyoff > qg) sc1[r] = -1e5f;
        }
      }

      float m8[8];
#pragma unroll
      for (int i = 0; i < 8; ++i)
        m8[i] = fmaxf(fmaxf(sc0[i], sc0[i + 8]), fmaxf(sc1[i], sc1[i + 8]));
#pragma unroll
      for (int st = 4; st >= 1; st >>= 1)
#pragma unroll
        for (int i = 0; i < st; ++i) m8[i] = fmaxf(m8[i], m8[i + st]);
      float mx = fmaxf(m8[0], __shfl_xor(m8[0], 32, 64));
      float mxs = mx * SC;

      if (__any(mxs > mrun + 8.f)) {
        float nm = fmaxf(mrun, mxs);
        float fs = fexp2(mrun - nm);
        mrun = nm;
        lrun *= fs;
#pragma unroll
        for (int i = 0; i < 16; ++i) { acc0[i] *= fs; acc1[i] *= fs; }
      }

      float p0[16], p1[16];
      const float nmn = -mrun;
#pragma unroll
      for (int i = 0; i < 16; ++i) {
        p0[i] = fexp2(__builtin_fmaf(sc0[i], SC, nmn));
        p1[i] = fexp2(__builtin_fmaf(sc1[i], SC, nmn));
      }
      float s8[8];
#pragma unroll
      for (int i = 0; i < 8; ++i) s8[i] = (p0[i] + p0[i + 8]) + (p1[i] + p1[i + 8]);
#pragma unroll
      for (int st = 4; st >= 1; st >>= 1)
#pragma unroll
        for (int i = 0; i < st; ++i) s8[i] += s8[i + st];
      lrun += s8[0] + __shfl_xor(s8[0], 32, 64);

      bf16x8 pf[4];
#pragma unroll
      for (int tt = 0; tt < 2; ++tt) {
        const float* pp = tt ? p1 : p0;
        unsigned wd[8];
#pragma unroll
        for (int j = 0; j < 8; ++j) wd[j] = cvt_pk_bf16(pp[2 * j], pp[2 * j + 1]);
        uv2 sA = __builtin_amdgcn_permlane32_swap(wd[0], wd[2], false, false);
        uv2 sB = __builtin_amdgcn_permlane32_swap(wd[1], wd[3], false, false);
        uv2 sC = __builtin_amdgcn_permlane32_swap(wd[4], wd[6], false, false);
        uv2 sD = __builtin_amdgcn_permlane32_swap(wd[5], wd[7], false, false);
        u32x4 f0 = {sA[0], sB[0], sA[1], sB[1]};
        u32x4 f1 = {sC[0], sD[0], sC[1], sD[1]};
        pf[tt * 2 + 0] = __builtin_bit_cast(bf16x8, f0);
        pf[tt * 2 + 1] = __builtin_bit_cast(bf16x8, f1);
      }

      __builtin_amdgcn_s_setprio(1);
#pragma unroll
      for (int ks = 0; ks < 4; ++ks) {
        int c = (ks * 16 + hh * 8) ^ ksw;
        bf16x8 vf0 = *(const bf16x8*)&Vc[l31 * 64 + c];
        bf16x8 vf1 = *(const bf16x8*)&Vc[(32 + l31) * 64 + c];
        acc0 = __builtin_amdgcn_mfma_f32_32x32x16_bf16(vf0, pf[ks], acc0, 0, 0, 0);
        acc1 = __builtin_amdgcn_mfma_f32_32x32x16_bf16(vf1, pf[ks], acc1, 0, 0, 0);
      }
      __builtin_amdgcn_s_setprio(0);
    }

    asm volatile("" ::: "memory");
    __builtin_amdgcn_s_barrier();
    cur ^= 1;
  }
#undef ASTAGE

  float* MRG = (float*)smem;
  float4* CH = (float4*)smem;
  if (half == 1) {
#pragma unroll
    for (int c = 0; c < 4; ++c) {
      float4 v0 = {acc0[4 * c + 0], acc0[4 * c + 1], acc0[4 * c + 2], acc0[4 * c + 3]};
      float4 v1 = {acc1[4 * c + 0], acc1[4 * c + 1], acc1[4 * c + 2], acc1[4 * c + 3]};
      CH[(wq4 * 8 + c) * 64 + lane] = v0;
      CH[(wq4 * 8 + 4 + c) * 64 + lane] = v1;
    }
    MRG[8192 + wq4 * 128 + lane * 2 + 0] = mrun;
    MRG[8192 + wq4 * 128 + lane * 2 + 1] = lrun;
  }
  __syncthreads();
  if (half == 0) {
    float m1 = MRG[8192 + wq4 * 128 + lane * 2 + 0];
    float l1 = MRG[8192 + wq4 * 128 + lane * 2 + 1];
    float m = fmaxf(mrun, m1);
    float f0 = fexp2(mrun - m), f1 = fexp2(m1 - m);
    float inv = 1.f / (lrun * f0 + l1 * f1);
    float a = f0 * inv, b = f1 * inv;
    size_t obase = (size_t)qg * 2048 + h * 64;
#pragma unroll
    for (int c = 0; c < 4; ++c) {
      float4 r0 = CH[(wq4 * 8 + c) * 64 + lane];
      float4 r1 = CH[(wq4 * 8 + 4 + c) * 64 + lane];
      u16x4 o0, o1;
      o0[0] = f2bf(acc0[4 * c + 0] * a + r0.x * b);
      o0[1] = f2bf(acc0[4 * c + 1] * a + r0.y * b);
      o0[2] = f2bf(acc0[4 * c + 2] * a + r0.z * b);
      o0[3] = f2bf(acc0[4 * c + 3] * a + r0.w * b);
      o1[0] = f2bf(acc1[4 * c + 0] * a + r1.x * b);
      o1[1] = f2bf(acc1[4 * c + 1] * a + r1.y * b);
      o1[2] = f2bf(acc1[4 * c + 2] * a + r1.z * b);
      o1[3] = f2bf(acc1[4 * c + 3] * a + r1.w * b);
      *(u16x4*)&attn_out[obase + 8 * c + 4 * hh] = o0;
      *(u16x4*)&attn_out[obase + 32 + 8 * c + 4 * hh] = o1;
    }
  }
}

extern "C" void kernel_launch(void* const* d_in, const int* in_sizes, int n_in,
                              void* d_out, int out_size, void* d_ws, size_t ws_size,
                              hipStream_t stream) {
  const float* x = (const float*)d_in[0];
  const float* fcos = (const float*)d_in[1];
  const float* fsin = (const float*)d_in[2];
  const float* wq = (const float*)d_in[4];
  const float* wk = (const float*)d_in[5];
  const float* wv = (const float*)d_in[6];
  const float* wo = (const float*)d_in[7];

  char* ws = (char*)d_ws;
  u16* xb    = (u16*)(ws);                    // 8 MB (reused as attn later)
  u16* wqkvT = (u16*)(ws + (8u << 20));       // 10 MB
  u16* woT   = (u16*)(ws + (18u << 20));      // 8 MB
  u16* QKV   = (u16*)(ws + (26u << 20));      // 10 MB
  u16* VT    = (u16*)(ws + (36u << 20));      // 1 MB
  u16* attn  = xb;

  dim3 tb32(32, 8);

  convert_f32_bf16<<<4096, 256, 0, stream>>>(x, xb, 2048 * 2048);
  transpose_wqkv<<<dim3(80, 64), tb32, 0, stream>>>(wq, wk, wv, wqkvT);
  transpose_f32_bf16<<<dim3(64, 64), tb32, 0, stream>>>(wo, woT, 2048, 2048);

  gemm_bt<false, true><<<dim3(20, 32), 512, 0, stream>>>(xb, wqkvT, QKV, 2048, 2560, 2048,
                                                         fcos, fsin);

  transpose_bf16<<<dim3(8, 64), tb32, 0, stream>>>(QKV + 2304, 2560, VT, 2048, 256);

  attn_kernel<<<dim3(32, 16), 512, 0, stream>>>(QKV, VT, attn);

  gemm_bt<true, false><<<dim3(16, 32), 512, 0, stream>>>(attn, woT, d_out, 2048, 2048, 2048,
                                                         nullptr, nullptr);
}